// Round 1
// baseline (924.858 us; speedup 1.0000x reference)
//
#include <hip/hip_runtime.h>

#define DEV static __device__ __forceinline__

typedef __bf16 bf16x8 __attribute__((ext_vector_type(8)));
typedef float f32x4 __attribute__((ext_vector_type(4)));
typedef unsigned short u16x8 __attribute__((ext_vector_type(8)));
typedef unsigned short u16x4 __attribute__((ext_vector_type(4)));

constexpr int Bv = 4, Lv = 2048, Dv = 1024, Hv = 8;
constexpr int BL = Bv * Lv;   // 8192

DEV float bf2f(unsigned short u) {
  union { unsigned int i; float f; } c; c.i = ((unsigned int)u) << 16; return c.f;
}
DEV unsigned short f2bf(float f) {  // RNE
  union { float f; unsigned int i; } c; c.f = f;
  unsigned int x = c.i;
  unsigned int r = (x >> 16) & 1u;
  x += 0x7fffu + r;
  return (unsigned short)(x >> 16);
}

// ---------------- weight conversion: Wq|Wk|Wv|Wg -> Wcat[4096][1024] bf16, Wo -> Wob ----
__global__ __launch_bounds__(256) void cvt_weights(
    const float* __restrict__ Wq, const float* __restrict__ Wk,
    const float* __restrict__ Wv, const float* __restrict__ Wg,
    const float* __restrict__ Wo,
    unsigned short* __restrict__ Wcat, unsigned short* __restrict__ Wob) {
  const int i = blockIdx.x * 256 + threadIdx.x;   // 0 .. 1310719
  const int NW4 = (4 * 1024 * 1024) / 4;          // 1048576 float4s in Wcat
  const float* src; unsigned short* dst;
  if (i < NW4) {
    const int e0 = i * 4;
    const int which = e0 >> 20;                   // 1M elements per matrix
    const int off = e0 & ((1 << 20) - 1);
    src = (which == 0 ? Wq : which == 1 ? Wk : which == 2 ? Wv : Wg) + off;
    dst = Wcat + e0;
  } else {
    const int e0 = (i - NW4) * 4;
    src = Wo + e0;
    dst = Wob + e0;
  }
  const float4 v = *(const float4*)src;
  u16x4 o;
  o[0] = f2bf(v.x); o[1] = f2bf(v.y); o[2] = f2bf(v.z); o[3] = f2bf(v.w);
  *(u16x4*)dst = o;
}

// ---------------- LayerNorm: x[8192][1024] f32 -> xn bf16 -------------------------------
__global__ __launch_bounds__(256) void ln_kernel(
    const float* __restrict__ x, const float* __restrict__ gamma,
    const float* __restrict__ beta, unsigned short* __restrict__ xnb) {
  const int row = blockIdx.x, tid = threadIdx.x;
  const float4 v = ((const float4*)(x + (size_t)row * 1024))[tid];
  float s = v.x + v.y + v.z + v.w;
  float q = v.x * v.x + v.y * v.y + v.z * v.z + v.w * v.w;
#pragma unroll
  for (int m = 1; m <= 32; m <<= 1) { s += __shfl_xor(s, m, 64); q += __shfl_xor(q, m, 64); }
  __shared__ float red[8];
  const int wave = tid >> 6, lane = tid & 63;
  if (lane == 0) { red[wave] = s; red[wave + 4] = q; }
  __syncthreads();
  s = red[0] + red[1] + red[2] + red[3];
  q = red[4] + red[5] + red[6] + red[7];
  const float mu = s * (1.0f / 1024.0f);
  const float var = q * (1.0f / 1024.0f) - mu * mu;
  const float rstd = rsqrtf(var + 1e-5f);
  const float4 g4 = ((const float4*)gamma)[tid];
  const float4 b4 = ((const float4*)beta)[tid];
  u16x4 o;
  o[0] = f2bf((v.x - mu) * rstd * g4.x + b4.x);
  o[1] = f2bf((v.y - mu) * rstd * g4.y + b4.y);
  o[2] = f2bf((v.z - mu) * rstd * g4.z + b4.z);
  o[3] = f2bf((v.w - mu) * rstd * g4.w + b4.w);
  ((u16x4*)(xnb + (size_t)row * 1024))[tid] = o;
}

// ---------------- bf16 GEMM: C[m][n] = sum_k A[m][k] * Bt[n][k] -------------------------
DEV void gld16(const void* g, void* l) {
  __builtin_amdgcn_global_load_lds((const __attribute__((address_space(1))) void*)g,
                                   (__attribute__((address_space(3))) void*)l, 16, 0, 0);
}

template <typename OUT_T, bool GATE>
__global__ __launch_bounds__(256) void gemm_bt(
    const unsigned short* __restrict__ A, const unsigned short* __restrict__ Bt,
    OUT_T* __restrict__ C, int M, int N, int K) {
  __shared__ unsigned short ldsA[128 * 32];
  __shared__ unsigned short ldsB[128 * 32];
  const int tiles_n = N >> 7;
  const int tm = blockIdx.x / tiles_n, tn = blockIdx.x % tiles_n;
  const int gm = tm << 7, gn = tn << 7;
  const int tid = threadIdx.x, wave = tid >> 6, lane = tid & 63;
  const int wm = (wave >> 1) << 6, wn = (wave & 1) << 6;   // 2x2 wave grid, 64x64 each
  f32x4 acc[4][4] = {};
  const int srow = lane >> 2, sk = (lane & 3) << 3;        // staging: 16 rows/wave, 8 elem chunks
  const unsigned short* Ag = A + (size_t)(gm + wave * 16 + srow) * K + sk;
  const unsigned short* Bg = Bt + (size_t)(gn + wave * 16 + srow) * K + sk;
  unsigned short* lA = &ldsA[wave * 512];
  unsigned short* lB = &ldsB[wave * 512];
  const int fr = lane & 15, fk = (lane >> 4) << 3;         // fragment read coords

  for (int k0 = 0; k0 < K; k0 += 32) {
    gld16(Ag + k0, lA);
    gld16(Ag + (size_t)64 * K + k0, lA + 2048);
    gld16(Bg + k0, lB);
    gld16(Bg + (size_t)64 * K + k0, lB + 2048);
    __syncthreads();
    bf16x8 af[4], bfr[4];
#pragma unroll
    for (int i = 0; i < 4; ++i) af[i] = *(const bf16x8*)&ldsA[(wm + i * 16 + fr) * 32 + fk];
#pragma unroll
    for (int j = 0; j < 4; ++j) bfr[j] = *(const bf16x8*)&ldsB[(wn + j * 16 + fr) * 32 + fk];
#pragma unroll
    for (int i = 0; i < 4; ++i)
#pragma unroll
      for (int j = 0; j < 4; ++j)
        acc[i][j] = __builtin_amdgcn_mfma_f32_16x16x32_bf16(af[i], bfr[j], acc[i][j], 0, 0, 0);
    __syncthreads();
  }
  // epilogue: D[i][j]: col = lane&15, row = 4*(lane>>4)+reg  [measured m89/m91]
  const bool gate = GATE && (gn >= 3 * 1024);
  const int er = (lane >> 4) << 2, ec = lane & 15;
#pragma unroll
  for (int i = 0; i < 4; ++i)
#pragma unroll
    for (int j = 0; j < 4; ++j)
#pragma unroll
      for (int r = 0; r < 4; ++r) {
        const int m = gm + wm + i * 16 + er + r;
        const int n = gn + wn + j * 16 + ec;
        float val = acc[i][j][r];
        if (gate) val = 1.0f / (1.0f + __expf(-val));  // store decay = sigmoid(gate_preact)
        if constexpr (sizeof(OUT_T) == 2) ((unsigned short*)C)[(size_t)m * N + n] = f2bf(val);
        else                              C[(size_t)m * N + n] = val;
      }
}

// ---------------- GLA scan --------------------------------------------------------------
// C1 row layout per (b,t): [ q(1024) | k(1024) | v(1024) | dec(1024) ], head-major cols.
// Recurrence independent per v-column -> parallelize (b,h,v-chunk of 16) = 256 blocks.
// Thread (v_i = tid>>4, kg = tid&15) owns S[k = kg*8 .. kg*8+7][v = vb*16+v_i] in regs.
__global__ __launch_bounds__(256) void gla_scan(
    const unsigned short* __restrict__ C1, unsigned short* __restrict__ yb,
    float* __restrict__ Sout) {
  const int blk = blockIdx.x;      // 0..255
  const int bh = blk >> 3;         // 0..31
  const int vb = blk & 7;          // 0..7
  const int b = bh >> 3, h = bh & 7;
  const int tid = threadIdx.x;
  const int v_i = tid >> 4;        // 0..15
  const int kg = tid & 15;         // 0..15
  const int vglob = vb * 16 + v_i; // 0..127
  const int kq0 = kg * 8;

  const unsigned short* p = C1 + (size_t)(b * Lv) * 4096 + h * 128;
  unsigned short* yp = yb + (size_t)(b * Lv) * 1024 + h * 128 + vglob;

  float S[8];
#pragma unroll
  for (int i = 0; i < 8; ++i) S[i] = 0.f;
  const float scale = 0.08838834764831845f;  // 128^-0.5

  u16x8 q8 = *(const u16x8*)(p + kq0);
  u16x8 k8 = *(const u16x8*)(p + 1024 + kq0);
  u16x8 d8 = *(const u16x8*)(p + 3072 + kq0);
  unsigned short vts = p[2048 + vglob];

  for (int t = 0; t < Lv; ++t) {
    const unsigned short* pn = (t + 1 < Lv) ? p + 4096 : p;   // clamp: branchless prefetch
    const u16x8 q8n = *(const u16x8*)(pn + kq0);
    const u16x8 k8n = *(const u16x8*)(pn + 1024 + kq0);
    const u16x8 d8n = *(const u16x8*)(pn + 3072 + kq0);
    const unsigned short vtsn = pn[2048 + vglob];

    const float vt = bf2f(vts);
    float o = 0.f;
#pragma unroll
    for (int kk = 0; kk < 8; ++kk) {
      const float dv = bf2f(d8[kk]);
      const float kv = bf2f(k8[kk]);
      const float qv = bf2f(q8[kk]);
      S[kk] = fmaf(S[kk], dv, kv * vt);
      o = fmaf(qv, S[kk], o);
    }
    o += __shfl_xor(o, 1, 64);
    o += __shfl_xor(o, 2, 64);
    o += __shfl_xor(o, 4, 64);
    o += __shfl_xor(o, 8, 64);
    if (kg == 0) *yp = f2bf(o * scale);
    yp += 1024;
    q8 = q8n; k8 = k8n; d8 = d8n; vts = vtsn;
    p = pn;
  }
#pragma unroll
  for (int kk = 0; kk < 8; ++kk)
    Sout[((size_t)bh * 128 + (kq0 + kk)) * 128 + vglob] = S[kk];
}

// ---------------- launch ----------------------------------------------------------------
extern "C" void kernel_launch(void* const* d_in, const int* in_sizes, int n_in,
                              void* d_out, int out_size, void* d_ws, size_t ws_size,
                              hipStream_t stream) {
  const float* x     = (const float*)d_in[0];
  const float* gamma = (const float*)d_in[1];
  const float* beta  = (const float*)d_in[2];
  const float* Wq    = (const float*)d_in[3];
  const float* Wk    = (const float*)d_in[4];
  const float* Wv    = (const float*)d_in[5];
  const float* Wg    = (const float*)d_in[6];
  const float* Wo    = (const float*)d_in[7];

  char* ws = (char*)d_ws;
  unsigned short* xnb  = (unsigned short*)(ws);               // 16 MB  [8192][1024]
  unsigned short* Wcat = (unsigned short*)(ws + 16777216);    //  8 MB  [4096][1024]
  unsigned short* Wob  = (unsigned short*)(ws + 25165824);    //  2 MB  [1024][1024]
  unsigned short* C1   = (unsigned short*)(ws + 27262976);    // 64 MB  [8192][4096]
  unsigned short* ybuf = (unsigned short*)(ws + 94371840);    // 16 MB  [8192][1024]

  float* outp = (float*)d_out;
  float* Sout = outp + (size_t)BL * 1024;                     // final_state tail

  cvt_weights<<<dim3(5120), dim3(256), 0, stream>>>(Wq, Wk, Wv, Wg, Wo, Wcat, Wob);
  ln_kernel<<<dim3(8192), dim3(256), 0, stream>>>(x, gamma, beta, xnb);
  gemm_bt<unsigned short, true><<<dim3(64 * 32), dim3(256), 0, stream>>>(
      xnb, Wcat, C1, 8192, 4096, 1024);
  gla_scan<<<dim3(256), dim3(256), 0, stream>>>(C1, ybuf, Sout);
  gemm_bt<float, false><<<dim3(64 * 8), dim3(256), 0, stream>>>(
      ybuf, Wob, outp, 8192, 1024, 1024);
}

// Round 2
// 337.958 us; speedup vs baseline: 2.7366x; 2.7366x over previous
//
#include <hip/hip_runtime.h>

#define DEV static __device__ __forceinline__

typedef __bf16 bf16x8 __attribute__((ext_vector_type(8)));
typedef float f32x4 __attribute__((ext_vector_type(4)));
typedef unsigned short u16x8 __attribute__((ext_vector_type(8)));
typedef unsigned short u16x4 __attribute__((ext_vector_type(4)));

constexpr int Bv = 4, Lv = 2048, Dv = 1024, Hv = 8;
constexpr int BL = Bv * Lv;   // 8192
constexpr int CH = 128;       // chunk length
constexpr int NC = Lv / CH;   // 16 chunks

DEV float bf2f(unsigned short u) {
  union { unsigned int i; float f; } c; c.i = ((unsigned int)u) << 16; return c.f;
}
DEV unsigned short f2bf(float f) {  // RNE
  union { float f; unsigned int i; } c; c.f = f;
  unsigned int x = c.i;
  unsigned int r = (x >> 16) & 1u;
  x += 0x7fffu + r;
  return (unsigned short)(x >> 16);
}

// ---------------- weight conversion: Wq|Wk|Wv|Wg -> Wcat[4096][1024] bf16, Wo -> Wob ----
__global__ __launch_bounds__(256) void cvt_weights(
    const float* __restrict__ Wq, const float* __restrict__ Wk,
    const float* __restrict__ Wv, const float* __restrict__ Wg,
    const float* __restrict__ Wo,
    unsigned short* __restrict__ Wcat, unsigned short* __restrict__ Wob) {
  const int i = blockIdx.x * 256 + threadIdx.x;
  const int NW4 = (4 * 1024 * 1024) / 4;
  const float* src; unsigned short* dst;
  if (i < NW4) {
    const int e0 = i * 4;
    const int which = e0 >> 20;
    const int off = e0 & ((1 << 20) - 1);
    src = (which == 0 ? Wq : which == 1 ? Wk : which == 2 ? Wv : Wg) + off;
    dst = Wcat + e0;
  } else {
    const int e0 = (i - NW4) * 4;
    src = Wo + e0;
    dst = Wob + e0;
  }
  const float4 v = *(const float4*)src;
  u16x4 o;
  o[0] = f2bf(v.x); o[1] = f2bf(v.y); o[2] = f2bf(v.z); o[3] = f2bf(v.w);
  *(u16x4*)dst = o;
}

// ---------------- LayerNorm: x[8192][1024] f32 -> xn bf16 -------------------------------
__global__ __launch_bounds__(256) void ln_kernel(
    const float* __restrict__ x, const float* __restrict__ gamma,
    const float* __restrict__ beta, unsigned short* __restrict__ xnb) {
  const int row = blockIdx.x, tid = threadIdx.x;
  const float4 v = ((const float4*)(x + (size_t)row * 1024))[tid];
  float s = v.x + v.y + v.z + v.w;
  float q = v.x * v.x + v.y * v.y + v.z * v.z + v.w * v.w;
#pragma unroll
  for (int m = 1; m <= 32; m <<= 1) { s += __shfl_xor(s, m, 64); q += __shfl_xor(q, m, 64); }
  __shared__ float red[8];
  const int wave = tid >> 6, lane = tid & 63;
  if (lane == 0) { red[wave] = s; red[wave + 4] = q; }
  __syncthreads();
  s = red[0] + red[1] + red[2] + red[3];
  q = red[4] + red[5] + red[6] + red[7];
  const float mu = s * (1.0f / 1024.0f);
  const float var = q * (1.0f / 1024.0f) - mu * mu;
  const float rstd = rsqrtf(var + 1e-5f);
  const float4 g4 = ((const float4*)gamma)[tid];
  const float4 b4 = ((const float4*)beta)[tid];
  u16x4 o;
  o[0] = f2bf((v.x - mu) * rstd * g4.x + b4.x);
  o[1] = f2bf((v.y - mu) * rstd * g4.y + b4.y);
  o[2] = f2bf((v.z - mu) * rstd * g4.z + b4.z);
  o[3] = f2bf((v.w - mu) * rstd * g4.w + b4.w);
  ((u16x4*)(xnb + (size_t)row * 1024))[tid] = o;
}

// ---------------- bf16 GEMM: C[m][n] = sum_k A[m][k] * Bt[n][k] -------------------------
DEV void gld16(const void* g, void* l) {
  __builtin_amdgcn_global_load_lds((const __attribute__((address_space(1))) void*)g,
                                   (__attribute__((address_space(3))) void*)l, 16, 0, 0);
}

template <typename OUT_T, bool GATE>
__global__ __launch_bounds__(256) void gemm_bt(
    const unsigned short* __restrict__ A, const unsigned short* __restrict__ Bt,
    OUT_T* __restrict__ C, int M, int N, int K) {
  __shared__ unsigned short ldsA[128 * 32];
  __shared__ unsigned short ldsB[128 * 32];
  const int tiles_n = N >> 7;
  const int tm = blockIdx.x / tiles_n, tn = blockIdx.x % tiles_n;
  const int gm = tm << 7, gn = tn << 7;
  const int tid = threadIdx.x, wave = tid >> 6, lane = tid & 63;
  const int wm = (wave >> 1) << 6, wn = (wave & 1) << 6;
  f32x4 acc[4][4] = {};
  const int srow = lane >> 2, sk = (lane & 3) << 3;
  const unsigned short* Ag = A + (size_t)(gm + wave * 16 + srow) * K + sk;
  const unsigned short* Bg = Bt + (size_t)(gn + wave * 16 + srow) * K + sk;
  unsigned short* lA = &ldsA[wave * 512];
  unsigned short* lB = &ldsB[wave * 512];
  const int fr = lane & 15, fk = (lane >> 4) << 3;

  for (int k0 = 0; k0 < K; k0 += 32) {
    gld16(Ag + k0, lA);
    gld16(Ag + (size_t)64 * K + k0, lA + 2048);
    gld16(Bg + k0, lB);
    gld16(Bg + (size_t)64 * K + k0, lB + 2048);
    __syncthreads();
    bf16x8 af[4], bfr[4];
#pragma unroll
    for (int i = 0; i < 4; ++i) af[i] = *(const bf16x8*)&ldsA[(wm + i * 16 + fr) * 32 + fk];
#pragma unroll
    for (int j = 0; j < 4; ++j) bfr[j] = *(const bf16x8*)&ldsB[(wn + j * 16 + fr) * 32 + fk];
#pragma unroll
    for (int i = 0; i < 4; ++i)
#pragma unroll
      for (int j = 0; j < 4; ++j)
        acc[i][j] = __builtin_amdgcn_mfma_f32_16x16x32_bf16(af[i], bfr[j], acc[i][j], 0, 0, 0);
    __syncthreads();
  }
  const bool gate = GATE && (gn >= 3 * 1024);
  const int er = (lane >> 4) << 2, ec = lane & 15;
#pragma unroll
  for (int i = 0; i < 4; ++i)
#pragma unroll
    for (int j = 0; j < 4; ++j)
#pragma unroll
      for (int r = 0; r < 4; ++r) {
        const int m = gm + wm + i * 16 + er + r;
        const int n = gn + wn + j * 16 + ec;
        float val = acc[i][j][r];
        if (gate) val = 1.0f / (1.0f + __expf(-val));  // decay = sigmoid(gate_preact)
        if constexpr (sizeof(OUT_T) == 2) ((unsigned short*)C)[(size_t)m * N + n] = f2bf(val);
        else                              C[(size_t)m * N + n] = val;
      }
}

// ---------------- Pass A: per-chunk local scan ------------------------------------------
// grid: bid = bh*32 + c*2 + vblk   (bh=0..31, c=0..15, vblk=0..1); 256 threads.
// thread: kg = tid&15 (k = kg*8..+7), v_i = tid>>4, owns v = vblk*64 + v_i*4 + {0..3}.
// Emits: o_local (ylocal, bf16), q~ = q*cumdecay*scale (Qt, bf16), M_c (bf16), Dtot (f32).
__global__ __launch_bounds__(256, 4) void gla_chunk_scan(
    const unsigned short* __restrict__ C1, unsigned short* __restrict__ ylocal,
    unsigned short* __restrict__ Qt, unsigned short* __restrict__ Mb,
    float* __restrict__ Dtot) {
  const int bid = blockIdx.x;
  const int vblk = bid & 1, c = (bid >> 1) & 15, bh = bid >> 5;
  const int b = bh >> 3, h = bh & 7;
  const int tid = threadIdx.x;
  const int kg = tid & 15, v_i = tid >> 4;
  const int kq0 = kg * 8;
  const int v0 = vblk * 64 + v_i * 4;
  const int t0 = c * CH;

  const unsigned short* p = C1 + (size_t)(b * Lv + t0) * 4096 + h * 128;
  unsigned short* yp = ylocal + (size_t)(b * Lv + t0) * 1024 + h * 128 + v0;
  unsigned short* qp = Qt + (size_t)(b * Lv + t0) * 1024 + h * 128 + kq0;
  const bool qwrite = (vblk == 0) && (v_i == 0);

  float S[8][4];
#pragma unroll
  for (int kk = 0; kk < 8; ++kk)
#pragma unroll
    for (int j = 0; j < 4; ++j) S[kk][j] = 0.f;
  float bprod[8];
#pragma unroll
  for (int kk = 0; kk < 8; ++kk) bprod[kk] = 1.f;
  const float scale = 0.08838834764831845f;  // 128^-0.5

  u16x8 q8 = *(const u16x8*)(p + kq0);
  u16x8 k8 = *(const u16x8*)(p + 1024 + kq0);
  u16x8 d8 = *(const u16x8*)(p + 3072 + kq0);
  u16x4 v4 = *(const u16x4*)(p + 2048 + v0);

  for (int t = 0; t < CH; ++t) {
    const unsigned short* pn = (t + 1 < CH) ? p + 4096 : p;
    const u16x8 q8n = *(const u16x8*)(pn + kq0);
    const u16x8 k8n = *(const u16x8*)(pn + 1024 + kq0);
    const u16x8 d8n = *(const u16x8*)(pn + 3072 + kq0);
    const u16x4 v4n = *(const u16x4*)(pn + 2048 + v0);

    float dv[8], kv[8], qv[8], vt[4];
#pragma unroll
    for (int kk = 0; kk < 8; ++kk) {
      dv[kk] = bf2f(d8[kk]); kv[kk] = bf2f(k8[kk]); qv[kk] = bf2f(q8[kk]);
    }
#pragma unroll
    for (int j = 0; j < 4; ++j) vt[j] = bf2f(v4[j]);

    float o[4] = {0.f, 0.f, 0.f, 0.f};
#pragma unroll
    for (int kk = 0; kk < 8; ++kk)
#pragma unroll
      for (int j = 0; j < 4; ++j) {
        S[kk][j] = fmaf(S[kk][j], dv[kk], kv[kk] * vt[j]);
        o[j] = fmaf(qv[kk], S[kk][j], o[j]);
      }
#pragma unroll
    for (int m = 1; m <= 8; m <<= 1)
#pragma unroll
      for (int j = 0; j < 4; ++j) o[j] += __shfl_xor(o[j], m, 64);
    if (kg == 0) {
      u16x4 yo;
#pragma unroll
      for (int j = 0; j < 4; ++j) yo[j] = f2bf(o[j] * scale);
      *(u16x4*)yp = yo;
    }
    yp += 1024;
    if (qwrite) {
      u16x8 qw;
#pragma unroll
      for (int kk = 0; kk < 8; ++kk) {
        bprod[kk] *= dv[kk];
        qw[kk] = f2bf(qv[kk] * bprod[kk] * scale);
      }
      *(u16x8*)qp = qw;
    }
    qp += 1024;
    q8 = q8n; k8 = k8n; d8 = d8n; v4 = v4n;
    p = pn;
  }
  // M_c = final local state (bf16)
#pragma unroll
  for (int kk = 0; kk < 8; ++kk) {
    u16x4 m4;
#pragma unroll
    for (int j = 0; j < 4; ++j) m4[j] = f2bf(S[kk][j]);
    *(u16x4*)&Mb[((size_t)(bh * NC + c) * 128 + kq0 + kk) * 128 + v0] = m4;
  }
  if (qwrite) {
#pragma unroll
    for (int kk = 0; kk < 8; ++kk)
      Dtot[(bh * NC + c) * 128 + kq0 + kk] = bprod[kk];
  }
}

// ---------------- Pass B: serial chunk combine + transpose ------------------------------
// grid: bid = bh*16 + kt*4 + vt (32 x 4 x 4 = 512 blocks); 32k x 32v tile per block.
__global__ __launch_bounds__(256) void chunk_combine(
    const unsigned short* __restrict__ Mb, const float* __restrict__ Dtot,
    unsigned short* __restrict__ SsT, float* __restrict__ Sfinal) {
  const int bid = blockIdx.x;
  const int vt = bid & 3, kt = (bid >> 2) & 3, bh = bid >> 4;
  const int k0 = kt * 32, v0 = vt * 32;
  const int tid = threadIdx.x;
  const int kk = tid >> 3, j0 = (tid & 7) * 4;   // read/update mapping
  const int vv = tid >> 3, k4 = (tid & 7) * 4;   // transpose-write mapping
  __shared__ unsigned short lt[32][36];
  float S[4] = {0.f, 0.f, 0.f, 0.f};
  for (int c = 0; c < NC; ++c) {
    // stage S (state at START of chunk c) transposed into LDS as bf16
#pragma unroll
    for (int j = 0; j < 4; ++j) lt[j0 + j][kk] = f2bf(S[j]);
    __syncthreads();
    *(u16x4*)&SsT[((size_t)(bh * NC + c) * 128 + v0 + vv) * 128 + k0 + k4] =
        *(const u16x4*)&lt[vv][k4];
    // update: S = S * Dtot_c + M_c
    const float d = Dtot[(bh * NC + c) * 128 + k0 + kk];
    const u16x4 m4 = *(const u16x4*)&Mb[((size_t)(bh * NC + c) * 128 + k0 + kk) * 128 + v0 + j0];
#pragma unroll
    for (int j = 0; j < 4; ++j) S[j] = fmaf(S[j], d, bf2f(m4[j]));
    __syncthreads();
  }
  float4 f; f.x = S[0]; f.y = S[1]; f.z = S[2]; f.w = S[3];
  *(float4*)&Sfinal[((size_t)bh * 128 + k0 + kk) * 128 + v0 + j0] = f;
}

// ---------------- Pass C: o += q~ @ S_c^T  (batched 128x128x128 MFMA, RMW) --------------
__global__ __launch_bounds__(256) void gemm_inter(
    const unsigned short* __restrict__ Qt, const unsigned short* __restrict__ SsT,
    unsigned short* __restrict__ ylocal) {
  __shared__ unsigned short ldsA[128 * 32];
  __shared__ unsigned short ldsB[128 * 32];
  const int bhc = blockIdx.x;            // bh*16 + c
  const int bh = bhc >> 4, c = bhc & 15;
  const int b = bh >> 3, h = bh & 7;
  const unsigned short* A = Qt + (size_t)(b * Lv + c * CH) * 1024 + h * 128;
  const unsigned short* Bt = SsT + (size_t)bhc * 128 * 128;
  unsigned short* Y = ylocal + (size_t)(b * Lv + c * CH) * 1024 + h * 128;
  const int tid = threadIdx.x, wave = tid >> 6, lane = tid & 63;
  const int wm = (wave >> 1) << 6, wn = (wave & 1) << 6;
  f32x4 acc[4][4] = {};
  const int srow = lane >> 2, sk = (lane & 3) << 3;
  const unsigned short* Ag = A + (size_t)(wave * 16 + srow) * 1024 + sk;
  const unsigned short* Bg = Bt + (size_t)(wave * 16 + srow) * 128 + sk;
  unsigned short* lA = &ldsA[wave * 512];
  unsigned short* lB = &ldsB[wave * 512];
  const int fr = lane & 15, fk = (lane >> 4) << 3;

  for (int k0 = 0; k0 < 128; k0 += 32) {
    gld16(Ag + k0, lA);
    gld16(Ag + (size_t)64 * 1024 + k0, lA + 2048);
    gld16(Bg + k0, lB);
    gld16(Bg + (size_t)64 * 128 + k0, lB + 2048);
    __syncthreads();
    bf16x8 af[4], bfr[4];
#pragma unroll
    for (int i = 0; i < 4; ++i) af[i] = *(const bf16x8*)&ldsA[(wm + i * 16 + fr) * 32 + fk];
#pragma unroll
    for (int j = 0; j < 4; ++j) bfr[j] = *(const bf16x8*)&ldsB[(wn + j * 16 + fr) * 32 + fk];
#pragma unroll
    for (int i = 0; i < 4; ++i)
#pragma unroll
      for (int j = 0; j < 4; ++j)
        acc[i][j] = __builtin_amdgcn_mfma_f32_16x16x32_bf16(af[i], bfr[j], acc[i][j], 0, 0, 0);
    __syncthreads();
  }
  const int er = (lane >> 4) << 2, ec = lane & 15;
#pragma unroll
  for (int i = 0; i < 4; ++i)
#pragma unroll
    for (int j = 0; j < 4; ++j)
#pragma unroll
      for (int r = 0; r < 4; ++r) {
        const int m = wm + i * 16 + er + r;
        const int n = wn + j * 16 + ec;
        const size_t idx = (size_t)m * 1024 + n;
        Y[idx] = f2bf(acc[i][j][r] + bf2f(Y[idx]));
      }
}

// ---------------- launch ----------------------------------------------------------------
extern "C" void kernel_launch(void* const* d_in, const int* in_sizes, int n_in,
                              void* d_out, int out_size, void* d_ws, size_t ws_size,
                              hipStream_t stream) {
  const float* x     = (const float*)d_in[0];
  const float* gamma = (const float*)d_in[1];
  const float* beta  = (const float*)d_in[2];
  const float* Wq    = (const float*)d_in[3];
  const float* Wk    = (const float*)d_in[4];
  const float* Wv    = (const float*)d_in[5];
  const float* Wg    = (const float*)d_in[6];
  const float* Wo    = (const float*)d_in[7];

  char* ws = (char*)d_ws;
  unsigned short* xnb  = (unsigned short*)(ws);               // 16 MB [8192][1024]; Qt aliases after gemm1
  unsigned short* Wcat = (unsigned short*)(ws + 16777216);    //  8 MB
  unsigned short* Wob  = (unsigned short*)(ws + 25165824);    //  2 MB
  unsigned short* C1   = (unsigned short*)(ws + 27262976);    // 64 MB [8192][4096]; SsT aliases after scan
  unsigned short* ybuf = (unsigned short*)(ws + 94371840);    // 16 MB [8192][1024]
  unsigned short* Mb   = (unsigned short*)(ws + 111149056);   // 16 MB [32*16][128][128]
  float*          Dtot = (float*)(ws + 127926272);            // 256 KB [32*16][128]
  unsigned short* Qt   = xnb;                                 // alias: xnb dead after gemm1
  unsigned short* SsT  = C1;                                  // alias: C1 dead after scan

  float* outp = (float*)d_out;
  float* Sout = outp + (size_t)BL * 1024;

  cvt_weights<<<dim3(5120), dim3(256), 0, stream>>>(Wq, Wk, Wv, Wg, Wo, Wcat, Wob);
  ln_kernel<<<dim3(8192), dim3(256), 0, stream>>>(x, gamma, beta, xnb);
  gemm_bt<unsigned short, true><<<dim3(64 * 32), dim3(256), 0, stream>>>(
      xnb, Wcat, C1, 8192, 4096, 1024);
  gla_chunk_scan<<<dim3(1024), dim3(256), 0, stream>>>(C1, ybuf, Qt, Mb, Dtot);
  chunk_combine<<<dim3(512), dim3(256), 0, stream>>>(Mb, Dtot, SsT, Sout);
  gemm_inter<<<dim3(512), dim3(256), 0, stream>>>(Qt, SsT, ybuf);
  gemm_bt<float, false><<<dim3(64 * 8), dim3(256), 0, stream>>>(
      ybuf, Wob, outp, 8192, 1024, 1024);
}